// Round 1
// baseline (946.539 us; speedup 1.0000x reference)
//
#include <hip/hip_runtime.h>
#include <hip/hip_cooperative_groups.h>

namespace cg = cooperative_groups;

namespace {

constexpr int kB = 64;
constexpr int kP = 25000;
constexpr int kT = 16;
constexpr int kC = 81;
constexpr int kRowsPerBlk = 64;            // ce_kernel rows per block
constexpr int kChunks = 16;                // prior chunks for match kernel
constexpr int kChunkP = (kP + kChunks - 1) / kChunks;  // 1563
constexpr float kThresh = 0.5f;

__device__ __forceinline__ float smooth_l1(float d) {
  float ad = fabsf(d);
  return ad < 1.0f ? 0.5f * d * d : ad - 0.5f;
}

// ---------------------------------------------------------------------------
// Fused match kernel (cooperative). Grid (kChunks, kB) x 256 = 1024 blocks =
// exactly 4 blocks/CU on 256 CUs; tiny LDS + __launch_bounds__(256,4) keeps
// co-residency guaranteed for grid.sync().
// Phase 1: per-prior best truth -> mcode kept in LDS (never touches global);
//          per-truth best prior via shfl butterfly + packed u64 atomicMax
//          (max iou, ties prefer smaller p == first occurrence, jnp.argmax).
// grid.sync()
// Phase 2: forcing (ascending j, last wins = torch loop order) + conf assign
//          + encode + smooth-L1. best_prior read back via atomicMax(p,0) RMW
//          so the value is coherent across XCDs.
// ---------------------------------------------------------------------------
__global__ __launch_bounds__(256, 4) void match_fused_kernel(
    const float* __restrict__ loc_data,   // [B,P,4]
    const float* __restrict__ priors,     // [P,4] (cx,cy,w,h)
    const float* __restrict__ targets,    // [B,T,5]
    unsigned long long* __restrict__ best_prior,  // [B,T], pre-zeroed
    unsigned char* __restrict__ code,     // [B,P] out: conf_t
    int* __restrict__ num_pos,            // [B], pre-zeroed, atomicAdd
    float* __restrict__ loss_l_acc) {     // [1], pre-zeroed
  const int chunk = blockIdx.x;
  const int b = blockIdx.y;
  const int tid = threadIdx.x;
  const int p0 = chunk * kChunkP;
  const int p1 = min(p0 + kChunkP, kP);

  __shared__ float tx0[kT], ty0[kT], tx1[kT], ty1[kT], tarea[kT], slab[kT];
  __shared__ unsigned char smcode[kChunkP];   // 1563 B, block-local mcode
  __shared__ float swv[kT][4];
  __shared__ int swi2[kT][4];
  __shared__ int s_bp[kT];
  __shared__ float swf[4];
  __shared__ int swi[4];

  if (tid < kT) {
    const float* tg = targets + (b * kT + tid) * 5;
    float x0 = tg[0], y0 = tg[1], x1 = tg[2], y1 = tg[3];
    tx0[tid] = x0; ty0[tid] = y0; tx1[tid] = x1; ty1[tid] = y1;
    tarea[tid] = (x1 - x0) * (y1 - y0);
    slab[tid] = tg[4];
  }
  __syncthreads();

  // ---- phase 1: IoU scan ----
  float bestv[kT];
  int besti[kT];
#pragma unroll
  for (int t = 0; t < kT; ++t) { bestv[t] = -1.0f; besti[t] = 0; }

  for (int p = p0 + tid; p < p1; p += 256) {
    float4 pr = reinterpret_cast<const float4*>(priors)[p];
    float px0 = pr.x - pr.z * 0.5f, py0 = pr.y - pr.w * 0.5f;
    float px1 = pr.x + pr.z * 0.5f, py1 = pr.y + pr.w * 0.5f;
    float parea = (px1 - px0) * (py1 - py0);
    float mv = -1.0f;
    int mt = 0;
#pragma unroll
    for (int t = 0; t < kT; ++t) {
      float lx = fmaxf(tx0[t], px0), ly = fmaxf(ty0[t], py0);
      float rx = fminf(tx1[t], px1), ry = fminf(ty1[t], py1);
      float w = fmaxf(rx - lx, 0.0f), h = fmaxf(ry - ly, 0.0f);
      float inter = w * h;
      float iou = inter / (tarea[t] + parea - inter);
      if (iou > bestv[t]) { bestv[t] = iou; besti[t] = p; }  // first idx wins
      if (iou > mv) { mv = iou; mt = t; }                    // first t wins
    }
    smcode[p - p0] = (unsigned char)(mt | (mv < kThresh ? 0x80 : 0));
  }

  // per-truth best prior: wave butterfly reduce, then cross-wave via LDS
#pragma unroll
  for (int t = 0; t < kT; ++t) {
    float v = bestv[t];
    int i = besti[t];
    for (int off = 32; off > 0; off >>= 1) {
      float v2 = __shfl_xor(v, off, 64);
      int i2 = __shfl_xor(i, off, 64);
      if (v2 > v || (v2 == v && i2 < i)) { v = v2; i = i2; }
    }
    if ((tid & 63) == 0) { swv[t][tid >> 6] = v; swi2[t][tid >> 6] = i; }
  }
  __syncthreads();
  if (tid < kT) {
    float v = swv[tid][0];
    int i = swi2[tid][0];
#pragma unroll
    for (int w = 1; w < 4; ++w) {
      float v2 = swv[tid][w];
      int i2 = swi2[tid][w];
      if (v2 > v || (v2 == v && i2 < i)) { v = v2; i = i2; }
    }
    // every thread in the chunk processed >= 1 prior, so v >= 0 always:
    // float bits are unsigned-monotone, pack (iou_bits<<32)|(~p)
    unsigned long long pk = ((unsigned long long)__float_as_uint(v) << 32) |
                            (unsigned long long)(0xFFFFFFFFu - (unsigned)i);
    atomicMax(&best_prior[b * kT + tid], pk);
  }

  cg::this_grid().sync();

  // ---- phase 2: forcing + conf + encode + smooth-L1 ----
  if (tid < kT) {
    // RMW read: coherent across XCDs regardless of L1/L2 state
    unsigned long long pk = atomicMax(&best_prior[b * kT + tid], 0ull);
    s_bp[tid] = (int)(0xFFFFFFFFu - (unsigned)(pk & 0xFFFFFFFFull));
  }
  __syncthreads();

  float lsum = 0.0f;
  int pcount = 0;
  for (int p = p0 + tid; p < p1; p += 256) {
    int c = smcode[p - p0];
    int mt = c & 0x0F;
    bool neg = (c & 0x80) != 0;
    bool forced = false;
#pragma unroll
    for (int j = 0; j < kT; ++j) {  // ascending j: last wins (torch loop order)
      if (s_bp[j] == p) { mt = j; forced = true; }
    }
    int conf = (!forced && neg) ? 0 : ((int)slab[mt] + 1);
    code[b * kP + p] = (unsigned char)conf;
    if (conf > 0) {
      ++pcount;
      float4 pr = reinterpret_cast<const float4*>(priors)[p];
      float mx0 = tx0[mt], my0 = ty0[mt], mx1 = tx1[mt], my1 = ty1[mt];
      float gcx = ((mx0 + mx1) * 0.5f - pr.x) / (0.1f * pr.z);
      float gcy = ((my0 + my1) * 0.5f - pr.y) / (0.1f * pr.w);
      float gw = logf((mx1 - mx0) / pr.z) / 0.2f;
      float gh = logf((my1 - my0) / pr.w) / 0.2f;
      float4 ld = reinterpret_cast<const float4*>(loc_data)[b * kP + p];
      lsum += smooth_l1(ld.x - gcx) + smooth_l1(ld.y - gcy) +
              smooth_l1(ld.z - gw) + smooth_l1(ld.w - gh);
    }
  }
  for (int off = 32; off > 0; off >>= 1) {
    lsum += __shfl_down(lsum, off, 64);
    pcount += __shfl_down(pcount, off, 64);
  }
  if ((tid & 63) == 0) { swf[tid >> 6] = lsum; swi[tid >> 6] = pcount; }
  __syncthreads();
  if (tid == 0) {
    float lt = swf[0] + swf[1] + swf[2] + swf[3];
    int pt = swi[0] + swi[1] + swi[2] + swi[3];
    if (lt != 0.0f) atomicAdd(loss_l_acc, lt);
    if (pt != 0) atomicAdd(&num_pos[b], pt);
  }
}

// ---------------------------------------------------------------------------
// Fallback pair (identical to the proven previous version) used only if the
// cooperative launch is rejected by the runtime/capture.
// ---------------------------------------------------------------------------
__global__ __launch_bounds__(256) void match1_kernel(
    const float* __restrict__ priors,
    const float* __restrict__ targets,
    unsigned char* __restrict__ mcode,
    unsigned long long* __restrict__ best_prior) {
  const int chunk = blockIdx.x;
  const int b = blockIdx.y;
  const int tid = threadIdx.x;
  const int p0 = chunk * kChunkP;
  const int p1 = min(p0 + kChunkP, kP);

  __shared__ float tx0[kT], ty0[kT], tx1[kT], ty1[kT], tarea[kT];
  __shared__ float smax[kT][256];
  __shared__ int sidx[kT][256];

  if (tid < kT) {
    const float* tg = targets + (b * kT + tid) * 5;
    float x0 = tg[0], y0 = tg[1], x1 = tg[2], y1 = tg[3];
    tx0[tid] = x0; ty0[tid] = y0; tx1[tid] = x1; ty1[tid] = y1;
    tarea[tid] = (x1 - x0) * (y1 - y0);
  }
  __syncthreads();

  float bestv[kT];
  int besti[kT];
#pragma unroll
  for (int t = 0; t < kT; ++t) { bestv[t] = -1.0f; besti[t] = 0; }

  for (int p = p0 + tid; p < p1; p += 256) {
    float4 pr = reinterpret_cast<const float4*>(priors)[p];
    float px0 = pr.x - pr.z * 0.5f, py0 = pr.y - pr.w * 0.5f;
    float px1 = pr.x + pr.z * 0.5f, py1 = pr.y + pr.w * 0.5f;
    float parea = (px1 - px0) * (py1 - py0);
    float mv = -1.0f;
    int mt = 0;
#pragma unroll
    for (int t = 0; t < kT; ++t) {
      float lx = fmaxf(tx0[t], px0), ly = fmaxf(ty0[t], py0);
      float rx = fminf(tx1[t], px1), ry = fminf(ty1[t], py1);
      float w = fmaxf(rx - lx, 0.0f), h = fmaxf(ry - ly, 0.0f);
      float inter = w * h;
      float iou = inter / (tarea[t] + parea - inter);
      if (iou > bestv[t]) { bestv[t] = iou; besti[t] = p; }
      if (iou > mv) { mv = iou; mt = t; }
    }
    mcode[b * kP + p] = (unsigned char)(mt | (mv < kThresh ? 0x80 : 0));
  }
#pragma unroll
  for (int t = 0; t < kT; ++t) { smax[t][tid] = bestv[t]; sidx[t][tid] = besti[t]; }
  __syncthreads();
  for (int s = 128; s > 0; s >>= 1) {
    if (tid < s) {
#pragma unroll
      for (int t = 0; t < kT; ++t) {
        float v1 = smax[t][tid], v2 = smax[t][tid + s];
        int i1 = sidx[t][tid], i2 = sidx[t][tid + s];
        if (v2 > v1 || (v2 == v1 && i2 < i1)) { smax[t][tid] = v2; sidx[t][tid] = i2; }
      }
    }
    __syncthreads();
  }
  if (tid < kT) {
    unsigned long long pk = ((unsigned long long)__float_as_uint(smax[tid][0]) << 32) |
                            (unsigned long long)(0xFFFFFFFFu - (unsigned)sidx[tid][0]);
    atomicMax(&best_prior[b * kT + tid], pk);
  }
}

__global__ __launch_bounds__(256) void match2_kernel(
    const float* __restrict__ loc_data,
    const float* __restrict__ priors,
    const float* __restrict__ targets,
    const unsigned long long* __restrict__ best_prior,
    unsigned char* __restrict__ code,
    int* __restrict__ num_pos,
    float* __restrict__ loss_l_acc) {
  const int chunk = blockIdx.x;
  const int b = blockIdx.y;
  const int tid = threadIdx.x;
  const int p0 = chunk * kChunkP;
  const int p1 = min(p0 + kChunkP, kP);

  __shared__ int s_bp[kT];
  __shared__ float sx0[kT], sy0[kT], sx1[kT], sy1[kT], slab[kT];
  __shared__ float swf[4];
  __shared__ int swi[4];

  if (tid < kT) {
    s_bp[tid] = (int)(0xFFFFFFFFu -
                      (unsigned)(best_prior[b * kT + tid] & 0xFFFFFFFFull));
    const float* tg = targets + (b * kT + tid) * 5;
    sx0[tid] = tg[0]; sy0[tid] = tg[1]; sx1[tid] = tg[2]; sy1[tid] = tg[3];
    slab[tid] = tg[4];
  }
  __syncthreads();

  float lsum = 0.0f;
  int pcount = 0;
  for (int p = p0 + tid; p < p1; p += 256) {
    int c = code[b * kP + p];
    int mt = c & 0x0F;
    bool neg = (c & 0x80) != 0;
    bool forced = false;
#pragma unroll
    for (int j = 0; j < kT; ++j) {
      if (s_bp[j] == p) { mt = j; forced = true; }
    }
    int conf = (!forced && neg) ? 0 : ((int)slab[mt] + 1);
    code[b * kP + p] = (unsigned char)conf;
    if (conf > 0) {
      ++pcount;
      float4 pr = reinterpret_cast<const float4*>(priors)[p];
      float mx0 = sx0[mt], my0 = sy0[mt], mx1 = sx1[mt], my1 = sy1[mt];
      float gcx = ((mx0 + mx1) * 0.5f - pr.x) / (0.1f * pr.z);
      float gcy = ((my0 + my1) * 0.5f - pr.y) / (0.1f * pr.w);
      float gw = logf((mx1 - mx0) / pr.z) / 0.2f;
      float gh = logf((my1 - my0) / pr.w) / 0.2f;
      float4 ld = reinterpret_cast<const float4*>(loc_data)[b * kP + p];
      lsum += smooth_l1(ld.x - gcx) + smooth_l1(ld.y - gcy) +
              smooth_l1(ld.z - gw) + smooth_l1(ld.w - gh);
    }
  }
  for (int off = 32; off > 0; off >>= 1) {
    lsum += __shfl_down(lsum, off, 64);
    pcount += __shfl_down(pcount, off, 64);
  }
  if ((tid & 63) == 0) { swf[tid >> 6] = lsum; swi[tid >> 6] = pcount; }
  __syncthreads();
  if (tid == 0) {
    float lt = swf[0] + swf[1] + swf[2] + swf[3];
    int pt = swi[0] + swi[1] + swi[2] + swi[3];
    if (lt != 0.0f) atomicAdd(loss_l_acc, lt);
    if (pt != 0) atomicAdd(&num_pos[b], pt);
  }
}

// ---------------------------------------------------------------------------
// Kernel B: per-(b,p) cross-entropy via logsumexp. Unchanged (BW-bound at the
// 518.4 MB conf_data read; coalesced float4 + LDS staging).
// ---------------------------------------------------------------------------
__global__ __launch_bounds__(256) void ce_kernel(
    const float* __restrict__ conf_data,      // [B*P, 81]
    const unsigned char* __restrict__ conf_t, // [B*P]
    float* __restrict__ loss_c,               // [B*P] out (0 at positives)
    float* __restrict__ pos_ce_acc) {         // [1] accumulate
  __shared__ float tile[kRowsPerBlk * kC];    // 20736 B
  __shared__ float swsum[4];
  const int tid = threadIdx.x;
  const long long base = (long long)blockIdx.x * (kRowsPerBlk * kC);
  const float4* src = reinterpret_cast<const float4*>(conf_data + base);
  float4* dst = reinterpret_cast<float4*>(tile);
#pragma unroll
  for (int i = 0; i < 6; ++i) {
    int idx = tid + i * 256;
    if (idx < kRowsPerBlk * kC / 4) dst[idx] = src[idx];
  }
  __syncthreads();

  const int r = tid >> 2;
  const int sub = tid & 3;
  const float* x = tile + r * kC;
  float m = -3.0e38f;
  for (int j = sub; j < kC; j += 4) m = fmaxf(m, x[j]);
  m = fmaxf(m, __shfl_xor(m, 1, 64));
  m = fmaxf(m, __shfl_xor(m, 2, 64));
  float s = 0.0f;
  for (int j = sub; j < kC; j += 4) s += __expf(x[j] - m);
  s += __shfl_xor(s, 1, 64);
  s += __shfl_xor(s, 2, 64);
  float posce = 0.0f;
  if (sub == 0) {
    const long long row = (long long)blockIdx.x * kRowsPerBlk + r;
    float lse = __logf(s) + m;
    int ct = conf_t[row];
    float ce = lse - x[ct];
    bool pos = ct > 0;
    loss_c[row] = pos ? 0.0f : ce;
    posce = pos ? ce : 0.0f;
  }
  for (int off = 32; off > 0; off >>= 1) posce += __shfl_down(posce, off, 64);
  if ((tid & 63) == 0) swsum[tid >> 6] = posce;
  __syncthreads();
  if (tid == 0) {
    float t = swsum[0] + swsum[1] + swsum[2] + swsum[3];
    if (t != 0.0f) atomicAdd(pos_ce_acc, t);
  }
}

// ---------------------------------------------------------------------------
// Kernel C: per-batch exact top-k sum of loss_c, now 1024 threads/block (4x
// less per-thread work per bit-search pass; 7 float4 register-cached).
// ---------------------------------------------------------------------------
__global__ __launch_bounds__(1024) void select_kernel(
    const float* __restrict__ loss_c,  // [B,P]
    const int* __restrict__ num_pos,   // [B]
    float* __restrict__ neg_ce_acc) {  // [1] accumulate
  const int b = blockIdx.x;
  const int tid = threadIdx.x;
  const int k = min(3 * num_pos[b], kP - 1);
  __shared__ int swi[16];
  __shared__ float swf[16];
  if (k <= 0) return;  // uniform branch per block

  constexpr int kV4 = kP / 4;                    // 6250
  constexpr int kPer = (kV4 + 1023) / 1024;      // 7
  const float4* v4 = reinterpret_cast<const float4*>(loss_c + (long long)b * kP);
  float4 lv[kPer];
#pragma unroll
  for (int j = 0; j < kPer; ++j) {
    int i = tid + j * 1024;
    lv[j] = (i < kV4) ? v4[i] : float4{0.0f, 0.0f, 0.0f, 0.0f};
    // zero padding is safe: cand > 0 in every count, and 0 is never > ans
  }

  unsigned int ans = 0;
  for (int bit = 30; bit >= 0; --bit) {  // bit 31 never set (nonneg floats)
    const unsigned int cand = ans | (1u << bit);
    int cnt = 0;
#pragma unroll
    for (int j = 0; j < kPer; ++j) {
      cnt += (__float_as_uint(lv[j].x) >= cand) + (__float_as_uint(lv[j].y) >= cand) +
             (__float_as_uint(lv[j].z) >= cand) + (__float_as_uint(lv[j].w) >= cand);
    }
    for (int off = 32; off > 0; off >>= 1) cnt += __shfl_down(cnt, off, 64);
    if ((tid & 63) == 0) swi[tid >> 6] = cnt;
    __syncthreads();
    int tot = 0;
#pragma unroll
    for (int w = 0; w < 16; ++w) tot += swi[w];  // broadcast reads, uniform
    if (tot >= k) ans = cand;
    __syncthreads();
  }
  // ans = k-th largest value's bits. Sum strict-greater, pad with ties.
  float sum = 0.0f;
  int cgt = 0;
#pragma unroll
  for (int j = 0; j < kPer; ++j) {
    if (__float_as_uint(lv[j].x) > ans) { sum += lv[j].x; ++cgt; }
    if (__float_as_uint(lv[j].y) > ans) { sum += lv[j].y; ++cgt; }
    if (__float_as_uint(lv[j].z) > ans) { sum += lv[j].z; ++cgt; }
    if (__float_as_uint(lv[j].w) > ans) { sum += lv[j].w; ++cgt; }
  }
  for (int off = 32; off > 0; off >>= 1) {
    sum += __shfl_down(sum, off, 64);
    cgt += __shfl_down(cgt, off, 64);
  }
  if ((tid & 63) == 0) { swf[tid >> 6] = sum; swi[tid >> 6] = cgt; }
  __syncthreads();
  if (tid == 0) {
    float st = 0.0f;
    int ct = 0;
#pragma unroll
    for (int w = 0; w < 16; ++w) { st += swf[w]; ct += swi[w]; }
    atomicAdd(neg_ce_acc, st + (float)(k - ct) * __uint_as_float(ans));
  }
}

// ---------------------------------------------------------------------------
// Kernel D: finalize the two scalar outputs.
// ---------------------------------------------------------------------------
__global__ void finalize_kernel(const int* __restrict__ num_pos,
                                const float* __restrict__ acc,  // [loss_l, pos_ce, neg_ce]
                                float* __restrict__ out) {
  int tid = threadIdx.x;  // 64 threads = 1 wave
  int np = num_pos[tid];
  for (int off = 32; off > 0; off >>= 1) np += __shfl_down(np, off, 64);
  if (tid == 0) {
    float N = fmaxf((float)np, 1.0f);
    out[0] = acc[0] / N;
    out[1] = (acc[1] + acc[2]) / N;
  }
}

}  // namespace

extern "C" void kernel_launch(void* const* d_in, const int* in_sizes, int n_in,
                              void* d_out, int out_size, void* d_ws, size_t ws_size,
                              hipStream_t stream) {
  const float* loc_data = (const float*)d_in[0];   // [B,P,4]
  const float* conf_data = (const float*)d_in[1];  // [B,P,81]
  const float* priors = (const float*)d_in[2];     // [P,4]
  const float* targets = (const float*)d_in[3];    // [B,T,5]
  float* out = (float*)d_out;                      // 2 floats

  // Workspace layout (~8.01 MB):
  //   [0, 6.4M)           loss_c float[B*P]
  //   [6.4M, 8.0M)        code u8[B*P]  (conf_t after match)
  //   [8.0M, +8192)       best_prior u64[B*T]          (zeroed)
  //   [+8192, +256)       num_pos int[B]               (zeroed)
  //   [+8448, +64)        acc: loss_l, pos_ce, neg_ce  (zeroed)
  char* ws = (char*)d_ws;
  float* loss_c = (float*)ws;
  unsigned char* code = (unsigned char*)(ws + 6400000);
  unsigned long long* best_prior = (unsigned long long*)(ws + 8000000);
  int* num_pos = (int*)(ws + 8008192);
  float* acc = (float*)(ws + 8008448);
  float* loss_l_acc = acc;

  hipMemsetAsync(ws + 8000000, 0, 8512, stream);

  void* margs[] = {(void*)&loc_data, (void*)&priors,    (void*)&targets,
                   (void*)&best_prior, (void*)&code,    (void*)&num_pos,
                   (void*)&loss_l_acc};
  hipError_t cerr = hipLaunchCooperativeKernel(
      (const void*)match_fused_kernel, dim3(kChunks, kB), dim3(256), margs, 0,
      stream);
  if (cerr != hipSuccess) {
    // fallback: proven two-kernel path (kernel boundary provides the sync)
    hipLaunchKernelGGL(match1_kernel, dim3(kChunks, kB), dim3(256), 0, stream,
                       priors, targets, code, best_prior);
    hipLaunchKernelGGL(match2_kernel, dim3(kChunks, kB), dim3(256), 0, stream,
                       loc_data, priors, targets, best_prior, code, num_pos, acc + 0);
  }
  hipLaunchKernelGGL(ce_kernel, dim3(kB * kP / kRowsPerBlk), dim3(256), 0, stream,
                     conf_data, code, loss_c, acc + 1);
  hipLaunchKernelGGL(select_kernel, dim3(kB), dim3(1024), 0, stream,
                     loss_c, num_pos, acc + 2);
  hipLaunchKernelGGL(finalize_kernel, dim3(1), dim3(64), 0, stream,
                     num_pos, acc, out);
}

// Round 2
// 830.311 us; speedup vs baseline: 1.1400x; 1.1400x over previous
//
#include <hip/hip_runtime.h>

namespace {

constexpr int kB = 64;
constexpr int kP = 25000;
constexpr int kT = 16;
constexpr int kC = 81;
constexpr int kRowsPerBlk = 64;            // ce_kernel rows per block
constexpr int kChunks = 16;                // prior chunks for match kernels
constexpr int kChunkP = (kP + kChunks - 1) / kChunks;  // 1563
constexpr float kThresh = 0.5f;

__device__ __forceinline__ float smooth_l1(float d) {
  float ad = fabsf(d);
  return ad < 1.0f ? 0.5f * d * d : ad - 0.5f;
}

// ---------------------------------------------------------------------------
// Kernel A1: per-prior best truth (computed ONCE), per-truth best prior via
// packed u64 atomicMax. Grid (kChunks, kB) x 256.
// mcode[b*P+p] = best_truth | (best_iou < 0.5 ? 0x80 : 0)
// best_prior[b*T+t] = atomicMax of (iou_bits << 32) | (0xFFFFFFFF - p)
//   -> max iou, ties prefer smaller p (first occurrence, matches jnp.argmax).
// Reduction is a shfl butterfly (no 32KB LDS tree, 1 barrier instead of 8) —
// this reduction ran verified (absmax 0.0) inside the round-1 fused kernel.
// ---------------------------------------------------------------------------
__global__ __launch_bounds__(256) void match1_kernel(
    const float* __restrict__ priors,     // [P,4] (cx,cy,w,h)
    const float* __restrict__ targets,    // [B,T,5]
    unsigned char* __restrict__ mcode,    // [B,P] out
    unsigned long long* __restrict__ best_prior) {  // [B,T], pre-zeroed
  const int chunk = blockIdx.x;
  const int b = blockIdx.y;
  const int tid = threadIdx.x;
  const int p0 = chunk * kChunkP;
  const int p1 = min(p0 + kChunkP, kP);

  __shared__ float tx0[kT], ty0[kT], tx1[kT], ty1[kT], tarea[kT];
  __shared__ float swv[kT][4];
  __shared__ int swi[kT][4];

  if (tid < kT) {
    const float* tg = targets + (b * kT + tid) * 5;
    float x0 = tg[0], y0 = tg[1], x1 = tg[2], y1 = tg[3];
    tx0[tid] = x0; ty0[tid] = y0; tx1[tid] = x1; ty1[tid] = y1;
    tarea[tid] = (x1 - x0) * (y1 - y0);
  }
  __syncthreads();

  float bestv[kT];
  int besti[kT];
#pragma unroll
  for (int t = 0; t < kT; ++t) { bestv[t] = -1.0f; besti[t] = 0; }

  for (int p = p0 + tid; p < p1; p += 256) {
    float4 pr = reinterpret_cast<const float4*>(priors)[p];
    float px0 = pr.x - pr.z * 0.5f, py0 = pr.y - pr.w * 0.5f;
    float px1 = pr.x + pr.z * 0.5f, py1 = pr.y + pr.w * 0.5f;
    float parea = (px1 - px0) * (py1 - py0);
    float mv = -1.0f;
    int mt = 0;
#pragma unroll
    for (int t = 0; t < kT; ++t) {
      float lx = fmaxf(tx0[t], px0), ly = fmaxf(ty0[t], py0);
      float rx = fminf(tx1[t], px1), ry = fminf(ty1[t], py1);
      float w = fmaxf(rx - lx, 0.0f), h = fmaxf(ry - ly, 0.0f);
      float inter = w * h;
      float iou = inter / (tarea[t] + parea - inter);
      if (iou > bestv[t]) { bestv[t] = iou; besti[t] = p; }  // first idx wins
      if (iou > mv) { mv = iou; mt = t; }                    // first t wins
    }
    mcode[b * kP + p] = (unsigned char)(mt | (mv < kThresh ? 0x80 : 0));
  }

  // per-truth best prior: wave butterfly, then cross-wave via tiny LDS
#pragma unroll
  for (int t = 0; t < kT; ++t) {
    float v = bestv[t];
    int i = besti[t];
    for (int off = 32; off > 0; off >>= 1) {
      float v2 = __shfl_xor(v, off, 64);
      int i2 = __shfl_xor(i, off, 64);
      if (v2 > v || (v2 == v && i2 < i)) { v = v2; i = i2; }
    }
    if ((tid & 63) == 0) { swv[t][tid >> 6] = v; swi[t][tid >> 6] = i; }
  }
  __syncthreads();
  if (tid < kT) {
    float v = swv[tid][0];
    int i = swi[tid][0];
#pragma unroll
    for (int w = 1; w < 4; ++w) {
      float v2 = swv[tid][w];
      int i2 = swi[tid][w];
      if (v2 > v || (v2 == v && i2 < i)) { v = v2; i = i2; }
    }
    // every thread in the chunk processed >= 1 prior, so v >= 0 always:
    // float bits are unsigned-monotone, pack (iou_bits<<32)|(~p)
    unsigned long long pk = ((unsigned long long)__float_as_uint(v) << 32) |
                            (unsigned long long)(0xFFFFFFFFu - (unsigned)i);
    atomicMax(&best_prior[b * kT + tid], pk);
  }
}

// ---------------------------------------------------------------------------
// Kernel A2: forcing + conf assignment + encode + smooth-L1 (no IoU recompute).
// Grid (kChunks, kB) x 256. code[] is read as mcode, overwritten as conf_t.
// Kernel boundary after match1 is the (free) grid-wide sync.
// ---------------------------------------------------------------------------
__global__ __launch_bounds__(256) void match2_kernel(
    const float* __restrict__ loc_data,   // [B,P,4]
    const float* __restrict__ priors,     // [P,4]
    const float* __restrict__ targets,    // [B,T,5]
    const unsigned long long* __restrict__ best_prior,  // [B,T]
    unsigned char* __restrict__ code,     // [B,P] in: mcode, out: conf_t
    int* __restrict__ num_pos,            // [B], pre-zeroed, atomicAdd
    float* __restrict__ loss_l_acc) {     // [1], pre-zeroed
  const int chunk = blockIdx.x;
  const int b = blockIdx.y;
  const int tid = threadIdx.x;
  const int p0 = chunk * kChunkP;
  const int p1 = min(p0 + kChunkP, kP);

  __shared__ int s_bp[kT];
  __shared__ float sx0[kT], sy0[kT], sx1[kT], sy1[kT], slab[kT];
  __shared__ float swf[4];
  __shared__ int swi[4];

  if (tid < kT) {
    s_bp[tid] = (int)(0xFFFFFFFFu -
                      (unsigned)(best_prior[b * kT + tid] & 0xFFFFFFFFull));
    const float* tg = targets + (b * kT + tid) * 5;
    sx0[tid] = tg[0]; sy0[tid] = tg[1]; sx1[tid] = tg[2]; sy1[tid] = tg[3];
    slab[tid] = tg[4];
  }
  __syncthreads();

  float lsum = 0.0f;
  int pcount = 0;
  for (int p = p0 + tid; p < p1; p += 256) {
    int c = code[b * kP + p];
    int mt = c & 0x0F;
    bool neg = (c & 0x80) != 0;
    bool forced = false;
#pragma unroll
    for (int j = 0; j < kT; ++j) {  // ascending j: last wins (torch loop order)
      if (s_bp[j] == p) { mt = j; forced = true; }
    }
    int conf = (!forced && neg) ? 0 : ((int)slab[mt] + 1);
    code[b * kP + p] = (unsigned char)conf;
    if (conf > 0) {
      ++pcount;
      float4 pr = reinterpret_cast<const float4*>(priors)[p];
      float mx0 = sx0[mt], my0 = sy0[mt], mx1 = sx1[mt], my1 = sy1[mt];
      float gcx = ((mx0 + mx1) * 0.5f - pr.x) / (0.1f * pr.z);
      float gcy = ((my0 + my1) * 0.5f - pr.y) / (0.1f * pr.w);
      float gw = logf((mx1 - mx0) / pr.z) / 0.2f;
      float gh = logf((my1 - my0) / pr.w) / 0.2f;
      float4 ld = reinterpret_cast<const float4*>(loc_data)[b * kP + p];
      lsum += smooth_l1(ld.x - gcx) + smooth_l1(ld.y - gcy) +
              smooth_l1(ld.z - gw) + smooth_l1(ld.w - gh);
    }
  }
  // wave reduce, then cross-wave via LDS
  for (int off = 32; off > 0; off >>= 1) {
    lsum += __shfl_down(lsum, off, 64);
    pcount += __shfl_down(pcount, off, 64);
  }
  if ((tid & 63) == 0) { swf[tid >> 6] = lsum; swi[tid >> 6] = pcount; }
  __syncthreads();
  if (tid == 0) {
    float lt = swf[0] + swf[1] + swf[2] + swf[3];
    int pt = swi[0] + swi[1] + swi[2] + swi[3];
    if (lt != 0.0f) atomicAdd(loss_l_acc, lt);
    if (pt != 0) atomicAdd(&num_pos[b], pt);
  }
}

// ---------------------------------------------------------------------------
// Kernel B: per-(b,p) cross-entropy via logsumexp. LDS-staged float4 loads,
// all 256 threads compute (4 lanes per row, quad shuffle reduce).
// Grid = B*P/kRowsPerBlk blocks x 256. BW-bound on the 518.4 MB conf read.
// ---------------------------------------------------------------------------
__global__ __launch_bounds__(256) void ce_kernel(
    const float* __restrict__ conf_data,      // [B*P, 81]
    const unsigned char* __restrict__ conf_t, // [B*P]
    float* __restrict__ loss_c,               // [B*P] out (0 at positives)
    float* __restrict__ pos_ce_acc) {         // [1] accumulate
  __shared__ float tile[kRowsPerBlk * kC];    // 20736 B
  __shared__ float swsum[4];
  const int tid = threadIdx.x;
  const long long base = (long long)blockIdx.x * (kRowsPerBlk * kC);
  const float4* src = reinterpret_cast<const float4*>(conf_data + base);
  float4* dst = reinterpret_cast<float4*>(tile);
#pragma unroll
  for (int i = 0; i < 6; ++i) {
    int idx = tid + i * 256;
    if (idx < kRowsPerBlk * kC / 4) dst[idx] = src[idx];
  }
  __syncthreads();

  const int r = tid >> 2;   // row within block, quads are wave-contiguous
  const int sub = tid & 3;
  const float* x = tile + r * kC;
  float m = -3.0e38f;
  for (int j = sub; j < kC; j += 4) m = fmaxf(m, x[j]);
  m = fmaxf(m, __shfl_xor(m, 1, 64));
  m = fmaxf(m, __shfl_xor(m, 2, 64));
  float s = 0.0f;
  for (int j = sub; j < kC; j += 4) s += __expf(x[j] - m);
  s += __shfl_xor(s, 1, 64);
  s += __shfl_xor(s, 2, 64);
  float posce = 0.0f;
  if (sub == 0) {
    const long long row = (long long)blockIdx.x * kRowsPerBlk + r;
    float lse = __logf(s) + m;
    int ct = conf_t[row];
    float ce = lse - x[ct];
    bool pos = ct > 0;
    loss_c[row] = pos ? 0.0f : ce;
    posce = pos ? ce : 0.0f;
  }
  for (int off = 32; off > 0; off >>= 1) posce += __shfl_down(posce, off, 64);
  if ((tid & 63) == 0) swsum[tid >> 6] = posce;
  __syncthreads();
  if (tid == 0) {
    float t = swsum[0] + swsum[1] + swsum[2] + swsum[3];
    if (t != 0.0f) atomicAdd(pos_ce_acc, t);  // positives are sparse
  }
}

// ---------------------------------------------------------------------------
// Kernel C: per-batch exact top-k sum of loss_c (256 threads, proven version).
// Finalize is fused via a last-block-done counter: after this block's neg-CE
// atomicAdd (device-scope, coherent) + __threadfence, the 64th arriving block
// reads everything back and writes the two outputs. Drops one dispatch.
// ---------------------------------------------------------------------------
__global__ __launch_bounds__(256) void select_kernel(
    const float* __restrict__ loss_c,  // [B,P]
    const int* __restrict__ num_pos,   // [B]
    float* __restrict__ acc,           // [loss_l, pos_ce, neg_ce]
    int* __restrict__ counter,         // [1], pre-zeroed
    float* __restrict__ out) {         // [2] final outputs
  const int b = blockIdx.x;
  const int tid = threadIdx.x;
  const int k = min(3 * num_pos[b], kP - 1);
  __shared__ int swi[4];
  __shared__ float swf[4];

  if (k > 0) {  // uniform branch per block
    constexpr int kV4 = kP / 4;                  // 6250
    constexpr int kPer = (kV4 + 255) / 256;      // 25
    const float4* v4 = reinterpret_cast<const float4*>(loss_c + (long long)b * kP);
    float4 lv[kPer];
#pragma unroll
    for (int j = 0; j < kPer; ++j) {
      int i = tid + j * 256;
      lv[j] = (i < kV4) ? v4[i] : float4{0.0f, 0.0f, 0.0f, 0.0f};
      // zero padding is safe: cand > 0 in every count, and 0 is never > ans
    }

    unsigned int ans = 0;
    for (int bit = 30; bit >= 0; --bit) {  // bit 31 never set (nonneg floats)
      const unsigned int cand = ans | (1u << bit);
      int cnt = 0;
#pragma unroll
      for (int j = 0; j < kPer; ++j) {
        cnt += (__float_as_uint(lv[j].x) >= cand) + (__float_as_uint(lv[j].y) >= cand) +
               (__float_as_uint(lv[j].z) >= cand) + (__float_as_uint(lv[j].w) >= cand);
      }
      for (int off = 32; off > 0; off >>= 1) cnt += __shfl_down(cnt, off, 64);
      if ((tid & 63) == 0) swi[tid >> 6] = cnt;
      __syncthreads();
      int tot = swi[0] + swi[1] + swi[2] + swi[3];  // uniform across block
      if (tot >= k) ans = cand;
      __syncthreads();
    }
    // ans = k-th largest value's bits. Sum strict-greater, pad with ties.
    float sum = 0.0f;
    int cgt = 0;
#pragma unroll
    for (int j = 0; j < kPer; ++j) {
      if (__float_as_uint(lv[j].x) > ans) { sum += lv[j].x; ++cgt; }
      if (__float_as_uint(lv[j].y) > ans) { sum += lv[j].y; ++cgt; }
      if (__float_as_uint(lv[j].z) > ans) { sum += lv[j].z; ++cgt; }
      if (__float_as_uint(lv[j].w) > ans) { sum += lv[j].w; ++cgt; }
    }
    for (int off = 32; off > 0; off >>= 1) {
      sum += __shfl_down(sum, off, 64);
      cgt += __shfl_down(cgt, off, 64);
    }
    if ((tid & 63) == 0) { swf[tid >> 6] = sum; swi[tid >> 6] = cgt; }
    __syncthreads();
    if (tid == 0) {
      float st = swf[0] + swf[1] + swf[2] + swf[3];
      int ct = swi[0] + swi[1] + swi[2] + swi[3];
      atomicAdd(acc + 2, st + (float)(k - ct) * __uint_as_float(ans));
    }
  }

  // last-block finalize: order = (my neg-CE add) -> fence -> counter bump
  __threadfence();
  if (tid == 0) {
    int done = atomicAdd(counter, 1);
    if (done == kB - 1) {
      int np = 0;
      for (int i = 0; i < kB; ++i) np += num_pos[i];  // written pre-launch, coherent
      float N = fmaxf((float)np, 1.0f);
      float neg = atomicAdd(acc + 2, 0.0f);  // RMW read: sees all prior adds
      out[0] = acc[0] / N;                   // written by match2 (pre-launch)
      out[1] = (acc[1] + neg) / N;           // acc[1] written by ce (pre-launch)
    }
  }
}

}  // namespace

extern "C" void kernel_launch(void* const* d_in, const int* in_sizes, int n_in,
                              void* d_out, int out_size, void* d_ws, size_t ws_size,
                              hipStream_t stream) {
  const float* loc_data = (const float*)d_in[0];   // [B,P,4]
  const float* conf_data = (const float*)d_in[1];  // [B,P,81]
  const float* priors = (const float*)d_in[2];     // [P,4]
  const float* targets = (const float*)d_in[3];    // [B,T,5]
  float* out = (float*)d_out;                      // 2 floats

  // Workspace layout (~8.01 MB):
  //   [0, 6.4M)           loss_c float[B*P]
  //   [6.4M, 8.0M)        code u8[B*P]  (mcode from match1, conf_t after match2)
  //   [8.0M, +8192)       best_prior u64[B*T]          (zeroed)
  //   [+8192, 256)        num_pos int[B]               (zeroed)
  //   [+8448, 64)         acc: loss_l, pos_ce, neg_ce  (zeroed)
  //   [+8512, 64)         counter int[1]               (zeroed)
  char* ws = (char*)d_ws;
  float* loss_c = (float*)ws;
  unsigned char* code = (unsigned char*)(ws + 6400000);
  unsigned long long* best_prior = (unsigned long long*)(ws + 8000000);
  int* num_pos = (int*)(ws + 8008192);
  float* acc = (float*)(ws + 8008448);
  int* counter = (int*)(ws + 8008512);

  hipMemsetAsync(ws + 8000000, 0, 8576, stream);
  hipLaunchKernelGGL(match1_kernel, dim3(kChunks, kB), dim3(256), 0, stream,
                     priors, targets, code, best_prior);
  hipLaunchKernelGGL(match2_kernel, dim3(kChunks, kB), dim3(256), 0, stream,
                     loc_data, priors, targets, best_prior, code, num_pos, acc + 0);
  hipLaunchKernelGGL(ce_kernel, dim3(kB * kP / kRowsPerBlk), dim3(256), 0, stream,
                     conf_data, code, loss_c, acc + 1);
  hipLaunchKernelGGL(select_kernel, dim3(kB), dim3(256), 0, stream,
                     loss_c, num_pos, acc, counter, out);
}